// Round 12
// baseline (798.093 us; speedup 1.0000x reference)
//
#include <hip/hip_runtime.h>
#include <hip/hip_bf16.h>
#include <hip/hip_fp16.h>

#define VOCAB 512
#define EMB   128
#define HID   64
#define BATCH 256
#define TLEN  1024
#define SEQ   16              // sequences per block (MFMA N dimension)
#define NBLK  (BATCH / SEQ)   // 16 blocks
#define CH    8               // steps per chunk (flag granularity)
#define NCHK  (TLEN / CH)     // 128 chunks
#define RS    32              // H0 ring depth in steps
#define RCHK  (RS / CH)       // 4 chunks per ring
#define HROW  72              // padded fp16 row (+8) -> 2-way-free banks

typedef _Float16 f16x8 __attribute__((ext_vector_type(8)));
typedef _Float16 f16x4 __attribute__((ext_vector_type(4)));
typedef float    f32x4 __attribute__((ext_vector_type(4)));

__device__ __forceinline__ float fast_tanh(float x) {
    float e = __expf(2.0f * x);
    return 1.0f - 2.0f / (e + 1.0f);
}
__device__ __forceinline__ void lds_fence() {
    asm volatile("s_waitcnt lgkmcnt(0)" ::: "memory");
}
__device__ __forceinline__ void compiler_fence() {
    asm volatile("" ::: "memory");
}
__device__ __forceinline__ void nap() { __builtin_amdgcn_s_sleep(1); }

// Load an A-operand fragment of W (fp32, row-major 64x64) as fp16.
// A[m][k]: m = lane&15 (row within 16-block), k = quad*8 + j  [HW-verified
// mapping, learn_hip m120 note]. row = 16*rblk + m, kbase = 32*chunk + quad*8.
__device__ __forceinline__ f16x8 load_wfrag(const float* __restrict__ W,
                                            int row, int kbase) {
    const float4* p = (const float4*)(W + row * HID + kbase);
    float4 u = p[0], v = p[1];
    f16x8 a;
    a[0] = (_Float16)u.x; a[1] = (_Float16)u.y;
    a[2] = (_Float16)u.z; a[3] = (_Float16)u.w;
    a[4] = (_Float16)v.x; a[5] = (_Float16)v.y;
    a[6] = (_Float16)v.z; a[7] = (_Float16)v.w;
    return a;
}

// ---------------------------------------------------------------------------
// Kernel 1: P0[v][i] = sum_e emb[v][e]*Wih0[i][e] + bih0[i] + bhh0[i]  (fp32)
// ---------------------------------------------------------------------------
__global__ void __launch_bounds__(64) p0_kernel(
    const float* __restrict__ emb,
    const float* __restrict__ wih0,
    const float* __restrict__ bih0,
    const float* __restrict__ bhh0,
    float* __restrict__ P0)
{
    const int v = blockIdx.x;
    const int i = threadIdx.x;
    const float4* er = (const float4*)(emb  + v * EMB);
    const float4* wr = (const float4*)(wih0 + i * EMB);
    float a0 = 0.f, a1 = 0.f, a2 = 0.f, a3 = 0.f;
    #pragma unroll
    for (int k = 0; k < EMB / 4; ++k) {
        float4 e4 = er[k];
        float4 w4 = wr[k];
        a0 = fmaf(e4.x, w4.x, a0);
        a1 = fmaf(e4.y, w4.y, a1);
        a2 = fmaf(e4.z, w4.z, a2);
        a3 = fmaf(e4.w, w4.w, a3);
    }
    P0[v * HID + i] = (a0 + a1) + (a2 + a3) + bih0[i] + bhh0[i];
}

// ---------------------------------------------------------------------------
// Kernel 2: MFMA-batched recurrence — 16 sequences per block, 2 waves.
// H(64x16) per layer; one step = 16x16x32_f16 MFMAs (4 row-blocks x K=2):
//   waveA: H0[t] = tanh(P0gather(C operand!) + Whh0*H0[t-1])        8 mfma
//   waveB: H1[t] = tanh(bias + Wih1*H0[t] + Whh1*H1[t-1])          16 mfma
// Per-step serial chain (~LDS hop + mfma + 16 tanh) is amortized over 16
// sequences — the single-seq variants (R5-R11) all plateaued at ~700-880
// cyc/step on that same chain for ONE sequence.
// Layouts (HW-verified, learn_hip m89/m120): C/D col=lane&15 row=quad*4+reg;
// A[m=lane&15][k=quad*8+j]; B[k=quad*8+j][n=lane&15].
// H transported fp16 in LDS (row stride 72 -> 2-way banks = free).
// Sync: chunk flags + lgkmcnt-only fences (proven R5-R11). No loop barriers.
// ---------------------------------------------------------------------------
__global__ void __launch_bounds__(128, 1) rnn_kernel(
    const int*   __restrict__ xs,
    const float* __restrict__ P0,
    const float* __restrict__ Whh0,
    const float* __restrict__ Wih1,
    const float* __restrict__ Whh1,
    const float* __restrict__ bih1,
    const float* __restrict__ bhh1,
    const float* __restrict__ W1,
    const float* __restrict__ b1,
    const float* __restrict__ W2,
    const float* __restrict__ b2,
    float*       __restrict__ out)
{
    __shared__ __half H0[RS][SEQ][HROW];   // 72 KiB  h0 ring (A -> B, + A self)
    __shared__ __half H1[2][SEQ][HROW];    // 4.5 KiB h1 ping-pong (B self)
    __shared__ int    flags[2];

    const int blk  = blockIdx.x;
    const int tid  = threadIdx.x;
    const int wv   = tid >> 6;
    const int lane = tid & 63;
    const int m    = lane & 15;    // A-row / B-col / C-col index
    const int quad = lane >> 4;

    // zero the initial-state slots (h[-1] = 0)
    if (wv == 0) {
        for (int i = lane; i < SEQ * HROW; i += 64)
            ((__half*)H0[RS - 1])[i] = __float2half(0.f);
    } else {
        for (int i = lane; i < SEQ * HROW; i += 64)
            ((__half*)H1[1])[i] = __float2half(0.f);
    }
    if (tid < 2) flags[tid] = 0;
    __syncthreads();                       // the ONLY barrier in the kernel

    volatile int* vf = (volatile int*)flags;

    if (wv == 0) {
        // ================= waveA : layer-0 recurrence =================
        f16x8 A[4][2];
        #pragma unroll
        for (int r = 0; r < 4; ++r)
            #pragma unroll
            for (int c = 0; c < 2; ++c)
                A[r][c] = load_wfrag(Whh0, 16 * r + m, 32 * c + quad * 8);

        // x / P0 prefetch pipeline: C-operand rows land straight in regs.
        const int* xp = xs + (blk * SEQ + m) * TLEN;
        int xv0 = xp[0], xv1 = xp[1], xq = xp[2];
        f32x4 aC[4], aN[4];
        #pragma unroll
        for (int r = 0; r < 4; ++r)
            aC[r] = *(const f32x4*)(P0 + xv0 * HID + 16 * r + quad * 4);
        #pragma unroll
        for (int r = 0; r < 4; ++r)
            aN[r] = *(const f32x4*)(P0 + xv1 * HID + 16 * r + quad * 4);

        #pragma unroll 1
        for (int k = 0; k < NCHK; ++k) {
            if (k >= RCHK) {                       // ring reuse guard
                while (vf[1] < k - (RCHK - 1)) nap();
                compiler_fence();
            }
            #pragma unroll
            for (int i = 0; i < CH; ++i) {
                const int t = k * CH + i;
                // prefetch t+2's C rows and t+3's x (vmcnt only)
                f32x4 a2[4];
                #pragma unroll
                for (int r = 0; r < 4; ++r)
                    a2[r] = *(const f32x4*)(P0 + xq * HID + 16 * r + quad * 4);
                int xqn = xp[(t + 3 < TLEN) ? (t + 3) : (TLEN - 1)];

                // B fragments of H0[t-1] (fp16, 2 x b128)
                const __half* hs = H0[(t + RS - 1) & (RS - 1)][m];
                f16x8 B0 = *(const f16x8*)(hs + quad * 8);
                f16x8 B1 = *(const f16x8*)(hs + 32 + quad * 8);

                #pragma unroll
                for (int r = 0; r < 4; ++r) {
                    f32x4 D = __builtin_amdgcn_mfma_f32_16x16x32_f16(
                        A[r][0], B0, aC[r], 0, 0, 0);
                    D = __builtin_amdgcn_mfma_f32_16x16x32_f16(
                        A[r][1], B1, D, 0, 0, 0);
                    f16x4 hv;
                    hv[0] = (_Float16)fast_tanh(D[0]);
                    hv[1] = (_Float16)fast_tanh(D[1]);
                    hv[2] = (_Float16)fast_tanh(D[2]);
                    hv[3] = (_Float16)fast_tanh(D[3]);
                    *(f16x4*)(&H0[t & (RS - 1)][m][16 * r + quad * 4]) = hv;
                }
                #pragma unroll
                for (int r = 0; r < 4; ++r) { aC[r] = aN[r]; aN[r] = a2[r]; }
                xq = xqn;
            }
            lds_fence();                           // DS only, NOT vmcnt
            if (lane == 0) vf[0] = k + 1;
        }
    } else {
        // ====== waveB : layer-1 projection + recurrence + MLP head ======
        f16x8 Ai[4][2], Ah[4][2];
        #pragma unroll
        for (int r = 0; r < 4; ++r)
            #pragma unroll
            for (int c = 0; c < 2; ++c) {
                Ai[r][c] = load_wfrag(Wih1, 16 * r + m, 32 * c + quad * 8);
                Ah[r][c] = load_wfrag(Whh1, 16 * r + m, 32 * c + quad * 8);
            }
        f32x4 Cb[4];                               // bias in C/D layout
        #pragma unroll
        for (int r = 0; r < 4; ++r) {
            const float* p1 = bih1 + 16 * r + quad * 4;
            const float* p2 = bhh1 + 16 * r + quad * 4;
            Cb[r][0] = p1[0] + p2[0]; Cb[r][1] = p1[1] + p2[1];
            Cb[r][2] = p1[2] + p2[2]; Cb[r][3] = p1[3] + p2[3];
        }

        #pragma unroll 1
        for (int k = 0; k < NCHK; ++k) {
            while (vf[0] < k + 1) nap();
            compiler_fence();
            #pragma unroll
            for (int i = 0; i < CH; ++i) {
                const int t = k * CH + i;
                const __half* h0s = H0[t & (RS - 1)][m];
                f16x8 B00 = *(const f16x8*)(h0s + quad * 8);
                f16x8 B01 = *(const f16x8*)(h0s + 32 + quad * 8);
                const __half* h1s = H1[(t + 1) & 1][m];
                f16x8 B10 = *(const f16x8*)(h1s + quad * 8);
                f16x8 B11 = *(const f16x8*)(h1s + 32 + quad * 8);

                #pragma unroll
                for (int r = 0; r < 4; ++r) {
                    f32x4 D = __builtin_amdgcn_mfma_f32_16x16x32_f16(
                        Ai[r][0], B00, Cb[r], 0, 0, 0);
                    D = __builtin_amdgcn_mfma_f32_16x16x32_f16(
                        Ai[r][1], B01, D, 0, 0, 0);
                    D = __builtin_amdgcn_mfma_f32_16x16x32_f16(
                        Ah[r][0], B10, D, 0, 0, 0);
                    D = __builtin_amdgcn_mfma_f32_16x16x32_f16(
                        Ah[r][1], B11, D, 0, 0, 0);
                    f16x4 hv;
                    hv[0] = (_Float16)fast_tanh(D[0]);
                    hv[1] = (_Float16)fast_tanh(D[1]);
                    hv[2] = (_Float16)fast_tanh(D[2]);
                    hv[3] = (_Float16)fast_tanh(D[3]);
                    *(f16x4*)(&H1[t & 1][m][16 * r + quad * 4]) = hv;
                }
            }
            lds_fence();                           // H0 reads consumed
            if (lane == 0) vf[1] = k + 1;
        }

        // ---- MLP head: y = relu(h1 @ W1^T + b1) @ W2^T + b2, 16 seqs ----
        lds_fence();
        const __half* hf = H1[(TLEN - 1) & 1][m];  // seq m's final h1 (fp16)
        const int ub = quad * 8;                   // this lane's 8 units
        float acc[8];
        #pragma unroll
        for (int uu = 0; uu < 8; ++uu) acc[uu] = b1[ub + uu];
        for (int k2 = 0; k2 < HID; ++k2) {
            float hk = __half2float(hf[k2]);
            #pragma unroll
            for (int uu = 0; uu < 8; ++uu)
                acc[uu] = fmaf(W1[(ub + uu) * HID + k2], hk, acc[uu]);
        }
        float r = 0.f;
        #pragma unroll
        for (int uu = 0; uu < 8; ++uu)
            r += fmaxf(acc[uu], 0.f) * W2[ub + uu];
        r += __shfl_down(r, 32);
        r += __shfl_down(r, 16);
        if (lane < 16) out[blk * SEQ + m] = r + b2[0];
    }
}

extern "C" void kernel_launch(void* const* d_in, const int* in_sizes, int n_in,
                              void* d_out, int out_size, void* d_ws, size_t ws_size,
                              hipStream_t stream)
{
    const int*   x    = (const int*)d_in[0];
    const float* emb  = (const float*)d_in[1];
    const float* Wih0 = (const float*)d_in[2];
    const float* Whh0 = (const float*)d_in[3];
    const float* bih0 = (const float*)d_in[4];
    const float* bhh0 = (const float*)d_in[5];
    const float* Wih1 = (const float*)d_in[6];
    const float* Whh1 = (const float*)d_in[7];
    const float* bih1 = (const float*)d_in[8];
    const float* bhh1 = (const float*)d_in[9];
    const float* W1   = (const float*)d_in[10];
    const float* b1   = (const float*)d_in[11];
    const float* W2   = (const float*)d_in[12];
    const float* b2   = (const float*)d_in[13];

    float* P0 = (float*)d_ws;   // 512*64*4 = 128 KiB scratch

    hipLaunchKernelGGL(p0_kernel, dim3(VOCAB), dim3(HID), 0, stream,
                       emb, Wih0, bih0, bhh0, P0);
    hipLaunchKernelGGL(rnn_kernel, dim3(NBLK), dim3(128), 0, stream,
                       x, P0, Whh0, Wih1, Whh1, bih1, bhh1,
                       W1, b1, W2, b2, (float*)d_out);
}